// Round 12
// baseline (218.577 us; speedup 1.0000x reference)
//
#include <hip/hip_runtime.h>

// Problem constants (from reference)
#define HH 4096
#define WW 4096
#define NB 1024
#define NCHUNK 256
#define CROWS 16          // HH / NCHUNK
#define IOU_T 0.5f

typedef unsigned long long u64;

// ---------------- workspace layout ------------------------------------------
constexpr size_t OFF_PART   = 0;                                   // double x NCHUNK*WW (8 MB)
constexpr size_t OFF_SC64   = OFF_PART   + (size_t)NCHUNK * WW * 8;// double x NB
constexpr size_t OFF_ORDER  = OFF_SC64   + (size_t)NB * 8;         // int x NB
constexpr size_t OFF_CTR    = OFF_ORDER  + (size_t)NB * 4;         // int (64 B pad)
constexpr size_t OFF_IOU    = OFF_CTR    + 64;                     // u64 x NB*16 (128 KB)
constexpr size_t OFF_RECSC  = OFF_IOU    + (size_t)NB * 16 * 8;    // double x NB
constexpr size_t OFF_RECSEL = OFF_RECSC  + (size_t)NB * 8;         // u64 x NB*16 (128 KB)
constexpr size_t OFF_CC     = OFF_RECSEL + (size_t)NB * 16 * 8;    // float x HH*WW (64 MB)
// total ~= 72.5 MB

// ---------------- kernels ---------------------------------------------------

// fused staging (setup folded in): each block owns one chunk of 16 rows and
// 1024 of 4096 columns; derives its rows' x-range union from bbox via LDS
// atomics (identity row indexing into Cc). ONE read of probs, float4 loads.
// 1024 blocks = 4 waves/SIMD device-wide. part holds raw per-chunk column
// sums (fp64) — NOT scanned; k_boxsum sums spanned chunks directly (R12:
// k_chunkscan deleted). Block 0 zeroes the k_group ctr.
__global__ void __launch_bounds__(256) k_stage(const float* __restrict__ probs,
        const float* __restrict__ bbox,
        double* __restrict__ part, float* __restrict__ Cc, int* __restrict__ ctr) {
    __shared__ int xlo_s[CROWS], xhi_s[CROWS];
    __shared__ int2 rng_s[CROWS];   // {q0, q1} col-quad range; {1,0} if unflagged
    int tid = blockIdx.x * 256 + threadIdx.x;   // NCHUNK * WW/4 threads
    int c  = tid >> 10;          // chunk (uniform per block)
    int xq = tid & 1023;         // col-quad index
    int t  = threadIdx.x;
    if (blockIdx.x == 0 && t == 0) *ctr = 0;
    if (t < CROWS) { xlo_s[t] = WW + 1; xhi_s[t] = -1; }
    __syncthreads();
    int r0 = c * CROWS;
    for (int i = t; i < NB; i += 256) {
        float4 bb = ((const float4*)bbox)[i];
        int x1 = min(max((int)floorf(bb.x), 0), WW);
        int y1 = min(max((int)floorf(bb.y), 0), HH);
        int x2 = min(max((int)floorf(bb.z), 0), WW);
        int y2 = min(max((int)floorf(bb.w), 0), HH);
        int ra = y1 - 1 - r0, rb = y2 - 1 - r0;
        if (ra >= 0 && ra < CROWS) { atomicMin(&xlo_s[ra], x1); atomicMax(&xhi_s[ra], x2); }
        if (rb >= 0 && rb < CROWS) { atomicMin(&xlo_s[rb], x1); atomicMax(&xhi_s[rb], x2); }
    }
    __syncthreads();
    if (t < CROWS) {
        int lo = xlo_s[t], hi = xhi_s[t];
        rng_s[t] = (hi >= 0) ? make_int2(lo >> 2, (hi + 3) >> 2) : make_int2(1, 0);
    }
    __syncthreads();
    const float4* p = (const float4*)probs + (size_t)r0 * (WW / 4) + xq;
    float4* Cc4 = (float4*)Cc;
    double a0 = 0.0, a1 = 0.0, a2 = 0.0, a3 = 0.0;
    for (int r = 0; r < CROWS; r += 8) {
        float4 q[8];
        #pragma unroll
        for (int k = 0; k < 8; k++) q[k] = p[(size_t)(r + k) * (WW / 4)];
        #pragma unroll
        for (int k = 0; k < 8; k++) {
            a0 += (double)q[k].x; a1 += (double)q[k].y;
            a2 += (double)q[k].z; a3 += (double)q[k].w;
            int2 d = rng_s[r + k];
            if (xq >= d.x && xq < d.y)
                Cc4[(size_t)(r0 + r + k) * (WW / 4) + xq] =
                    make_float4((float)a0, (float)a1, (float)a2, (float)a3);
        }
    }
    double2* pp = (double2*)(part + (size_t)c * WW) + xq * 2;
    pp[0] = make_double2(a0, a1);
    pp[1] = make_double2(a2, a3);
}

// per-box rectangle sum: 256 threads (4 waves) per box. Column value:
//   prefix(y2-1) - prefix(y1-1)
//     = sum_{cc in [c1,c2)} part[cc][x] + Cc[y2-1][x] - Cc[y1-1][x]
// (part is UNSCANNED per-chunk sums; the cc-loop is coalesced 8 B/lane
// wave-loads from the L2-resident 8 MB part buffer — replaces k_chunkscan.)
__global__ void __launch_bounds__(256) k_boxsum(const float* __restrict__ bbox,
                         const float* __restrict__ obj,
                         const float* __restrict__ Cc,
                         const double* __restrict__ part,
                         double* __restrict__ sc64) {
    int i = blockIdx.x;
    int t = threadIdx.x;
    float4 bb = ((const float4*)bbox)[i];
    int x1 = min(max((int)floorf(bb.x), 0), WW);
    int y1 = min(max((int)floorf(bb.y), 0), HH);
    int x2 = min(max((int)floorf(bb.z), 0), WW);
    int y2 = min(max((int)floorf(bb.w), 0), HH);
    bool h1 = (y1 >= 1), h2 = (y2 >= 1);
    int c2 = h2 ? ((y2 - 1) >> 4) : 0;
    int cs = h1 ? ((y1 - 1) >> 4) : 0;      // start chunk of the part-range
    const float* r2 = Cc + (size_t)(h2 ? (y2 - 1) : 0) * WW;
    const float* r1 = Cc + (size_t)(h1 ? (y1 - 1) : 0) * WW;
    double s = 0.0;
    if (h2) {
        for (int x = x1 + t; x < x2; x += 256) {
            double col = (double)r2[x];
            if (h1) col -= (double)r1[x];
            for (int cc = cs; cc < c2; cc++)
                col += part[(size_t)cc * WW + x];
            s += col;
        }
    }
    __shared__ double red[4];
    #pragma unroll
    for (int off = 32; off > 0; off >>= 1) s += __shfl_down(s, off);
    if ((t & 63) == 0) red[t >> 6] = s;
    __syncthreads();
    if (t == 0) {
        double tot = red[0] + red[1] + red[2] + red[3];
        long long cnt = (long long)(y2 - y1) * (long long)(x2 - x1);
        if (cnt < 1) cnt = 1;
        sc64[i] = 0.5 * ((double)obj[i] + tot / (double)cnt);
    }
}

// stable descending rank sort, 8 blocks x 128 threads; per-block LDS score
// copy; sequential j loop -> all lanes broadcast-read the same s[j] (no bank
// conflicts).
__global__ void __launch_bounds__(128) k_rank(const double* __restrict__ sc64,
                                              int* __restrict__ order) {
    __shared__ double s[NB];   // 8 KB
    int t = threadIdx.x;
    for (int k = t; k < NB; k += 128) s[k] = sc64[k];
    __syncthreads();
    int i = blockIdx.x * 128 + t;
    double si = s[i];
    int rank = 0;
    #pragma unroll 8
    for (int j = 0; j < NB; j++) {
        double sj = s[j];
        rank += (sj > si) || (sj == si && j < i);
    }
    order[rank] = i;
}

// IoU(sorted_i, sorted_j) > 0.5 bit matrix via order-indirection (order 4 KB,
// bbox 16 KB — L1/L2 resident). 4096 blocks. One u64 word per 64 j's.
__global__ void k_iou(const int* __restrict__ order, const float* __restrict__ bbox,
                      u64* __restrict__ ioub) {
    int tid = blockIdx.x * blockDim.x + threadIdx.x; // NB*NB threads
    int i = tid >> 10;
    int j = tid & (NB - 1);
    float4 a = ((const float4*)bbox)[order[i]];
    float4 b = ((const float4*)bbox)[order[j]];
    float ai = (a.z - a.x) * (a.w - a.y);
    float aj = (b.z - b.x) * (b.w - b.y);
    float ix1 = fmaxf(a.x, b.x), iy1 = fmaxf(a.y, b.y);
    float ix2 = fminf(a.z, b.z), iy2 = fminf(a.w, b.w);
    float iw = fmaxf(ix2 - ix1, 0.0f), ih = fmaxf(iy2 - iy1, 0.0f);
    float inter = iw * ih;
    float iou_v = inter / (ai + aj - inter);
    bool bit = iou_v > IOU_T;
    u64 m = __ballot(bit);
    if ((threadIdx.x & 63) == 0) ioub[(size_t)i * 16 + (j >> 6)] = m;
}

// greedy grouping, one thread per start, 16 blocks x 64 threads, with the
// final last-argmax + output scatter fused into the LAST block to finish
// (device-scope atomic counter). Register masks + ctz scan walk the SAME
// increasing-j greedy order as the reference (inc updated per add).
// Record rule: rec iff size==K and the last add happened at j <= NB-2
// (check-before-add semantics).
__global__ void __launch_bounds__(64) k_group(const u64* __restrict__ ioub,
                        const int* __restrict__ order,
                        const double* __restrict__ sc64,
                        const int* __restrict__ counts,
                        double* __restrict__ recsc,
                        u64* __restrict__ recsel,
                        int* __restrict__ ctr,
                        float* __restrict__ out) {
    __shared__ double ssd_s[NB];   // 8 KB, sorted scores
    __shared__ int lastflag;
    int t = threadIdx.x;
    int i = blockIdx.x * 64 + t;   // start index (sorted domain)
    for (int k = t; k < NB; k += 64) ssd_s[k] = sc64[order[k]];
    __syncthreads();
    int K = counts[0];
    u64 inc[16], sel[16];
    int wi = i >> 6, bi = i & 63;
    #pragma unroll
    for (int w = 0; w < 16; w++) {
        inc[w] = ioub[(size_t)i * 16 + w];
        sel[w] = (w == wi) ? (1ULL << bi) : 0ULL;
    }
    int size = 1;
    double score = ssd_s[i];
    int last = i;
    #pragma unroll
    for (int w = 0; w < 16; w++) {
        if (w < wi || size >= K) continue;
        u64 avail = ~inc[w];
        if (w == wi) avail &= (bi == 63) ? 0ULL : (~0ULL << (bi + 1));
        while (avail != 0ULL && size < K) {
            int b = __builtin_ctzll(avail);
            int j = (w << 6) + b;
            sel[w] |= 1ULL << b;
            size++;
            score += ssd_s[j];
            last = j;
            const u64* rj = ioub + (size_t)j * 16;
            #pragma unroll
            for (int w2 = 0; w2 < 16; w2++) inc[w2] |= rj[w2];
            avail &= ~inc[w];          // row j's own bits clear b et al.
            avail &= ~(1ULL << b);     // safety
        }
    }
    int rec = (size == K) && (last < NB - 1);
    recsc[i] = rec ? score : -1e300;
    #pragma unroll
    for (int w = 0; w < 16; w++) recsel[(size_t)i * 16 + w] = sel[w];
    __threadfence();               // device-scope release of recsc/recsel
    if (t == 0) lastflag = (atomicAdd(ctr, 1) == (int)gridDim.x - 1);
    __syncthreads();
    if (!lastflag) return;
    __threadfence();               // acquire side: see all blocks' writes
    // final: max recorded score, ties -> LAST index (last-argmax rule)
    double bs = -1e301; int bidx = 0;
    for (int m = 0; m < 16; m++) {
        int k = t * 16 + m;        // increasing k; >= keeps the last
        double v = recsc[k];
        if (v >= bs) { bs = v; bidx = k; }
    }
    #pragma unroll
    for (int off = 32; off > 0; off >>= 1) {
        double ob = __shfl_down(bs, off);
        int oi = __shfl_down(bidx, off);
        if (ob > bs || (ob == bs && oi > bidx)) { bs = ob; bidx = oi; }
    }
    bs = __shfl(bs, 0);
    bidx = __shfl(bidx, 0);
    int any = bs > -1e299;
    for (int k = t; k < NB; k += 64) {
        float v = 0.0f;
        if (any && ((recsel[(size_t)bidx * 16 + (k >> 6)] >> (k & 63)) & 1ULL))
            v = (float)ssd_s[k];
        out[k] = v;
    }
}

// ---------------- host entry ------------------------------------------------

extern "C" void kernel_launch(void* const* d_in, const int* in_sizes, int n_in,
                              void* d_out, int out_size, void* d_ws, size_t ws_size,
                              hipStream_t stream) {
    const float* bbox  = (const float*)d_in[0];
    const float* obj   = (const float*)d_in[1];
    const float* probs = (const float*)d_in[2];
    const int*   counts = (const int*)d_in[3];
    float* out = (float*)d_out;

    char* w = (char*)d_ws;
    double* part    = (double*)(w + OFF_PART);
    double* sc64    = (double*)(w + OFF_SC64);
    int*    order   = (int*)(w + OFF_ORDER);
    int*    ctr     = (int*)(w + OFF_CTR);
    u64*    ioub    = (u64*)(w + OFF_IOU);
    double* recsc   = (double*)(w + OFF_RECSC);
    u64*    recsel  = (u64*)(w + OFF_RECSEL);
    float*  Cc      = (float*)(w + OFF_CC);

    k_stage<<<(NCHUNK * WW / 4) / 256, 256, 0, stream>>>(probs, bbox, part, Cc, ctr);
    k_boxsum<<<NB, 256, 0, stream>>>(bbox, obj, Cc, part, sc64);
    k_rank<<<NB / 128, 128, 0, stream>>>(sc64, order);
    k_iou<<<(NB * NB) / 256, 256, 0, stream>>>(order, bbox, ioub);
    k_group<<<NB / 64, 64, 0, stream>>>(ioub, order, sc64, counts, recsc, recsel,
                                        ctr, out);
}

// Round 13
// 173.702 us; speedup vs baseline: 1.2583x; 1.2583x over previous
//
#include <hip/hip_runtime.h>

// Problem constants (from reference)
#define HH 4096
#define WW 4096
#define NB 1024
#define NCHUNK 256
#define CROWS 16          // HH / NCHUNK
#define IOU_T 0.5f

typedef unsigned long long u64;

// ---------------- workspace layout ------------------------------------------
constexpr size_t OFF_PART   = 0;                                   // double x NCHUNK*WW (8 MB)
constexpr size_t OFF_SC64   = OFF_PART   + (size_t)NCHUNK * WW * 8;// double x NB
constexpr size_t OFF_ORDER  = OFF_SC64   + (size_t)NB * 8;         // int x NB
constexpr size_t OFF_CTR    = OFF_ORDER  + (size_t)NB * 4;         // int (64 B pad)
constexpr size_t OFF_IOU    = OFF_CTR    + 64;                     // u64 x NB*16 (128 KB)
constexpr size_t OFF_RECSC  = OFF_IOU    + (size_t)NB * 16 * 8;    // double x NB
constexpr size_t OFF_RECSEL = OFF_RECSC  + (size_t)NB * 8;         // u64 x NB*16 (128 KB)
constexpr size_t OFF_CC     = OFF_RECSEL + (size_t)NB * 16 * 8;    // float x HH*WW (64 MB)
// total ~= 72.5 MB

// ---------------- kernels ---------------------------------------------------

// fused staging (setup folded in): each block owns one chunk of 16 rows and
// 1024 of 4096 columns; derives its rows' x-range union from bbox via LDS
// atomics (identity row indexing into Cc). ONE read of probs, float4 loads.
// 1024 blocks = 4 waves/SIMD device-wide (256-block shape was 1 wave/SIMD
// and latency-bound). Block 0 zeroes the k_group ctr.
// R13: exact revert to R11 — R12's scan-free boxsum built a ~34-deep
// dependent L2 load chain and cost 76 us; the 3 us chunkscan kernel is the
// right trade.
__global__ void __launch_bounds__(256) k_stage(const float* __restrict__ probs,
        const float* __restrict__ bbox,
        double* __restrict__ part, float* __restrict__ Cc, int* __restrict__ ctr) {
    __shared__ int xlo_s[CROWS], xhi_s[CROWS];
    __shared__ int2 rng_s[CROWS];   // {q0, q1} col-quad range; {1,0} if unflagged
    int tid = blockIdx.x * 256 + threadIdx.x;   // NCHUNK * WW/4 threads
    int c  = tid >> 10;          // chunk (uniform per block)
    int xq = tid & 1023;         // col-quad index
    int t  = threadIdx.x;
    if (blockIdx.x == 0 && t == 0) *ctr = 0;
    if (t < CROWS) { xlo_s[t] = WW + 1; xhi_s[t] = -1; }
    __syncthreads();
    int r0 = c * CROWS;
    for (int i = t; i < NB; i += 256) {
        float4 bb = ((const float4*)bbox)[i];
        int x1 = min(max((int)floorf(bb.x), 0), WW);
        int y1 = min(max((int)floorf(bb.y), 0), HH);
        int x2 = min(max((int)floorf(bb.z), 0), WW);
        int y2 = min(max((int)floorf(bb.w), 0), HH);
        int ra = y1 - 1 - r0, rb = y2 - 1 - r0;
        if (ra >= 0 && ra < CROWS) { atomicMin(&xlo_s[ra], x1); atomicMax(&xhi_s[ra], x2); }
        if (rb >= 0 && rb < CROWS) { atomicMin(&xlo_s[rb], x1); atomicMax(&xhi_s[rb], x2); }
    }
    __syncthreads();
    if (t < CROWS) {
        int lo = xlo_s[t], hi = xhi_s[t];
        rng_s[t] = (hi >= 0) ? make_int2(lo >> 2, (hi + 3) >> 2) : make_int2(1, 0);
    }
    __syncthreads();
    const float4* p = (const float4*)probs + (size_t)r0 * (WW / 4) + xq;
    float4* Cc4 = (float4*)Cc;
    double a0 = 0.0, a1 = 0.0, a2 = 0.0, a3 = 0.0;
    for (int r = 0; r < CROWS; r += 8) {
        float4 q[8];
        #pragma unroll
        for (int k = 0; k < 8; k++) q[k] = p[(size_t)(r + k) * (WW / 4)];
        #pragma unroll
        for (int k = 0; k < 8; k++) {
            a0 += (double)q[k].x; a1 += (double)q[k].y;
            a2 += (double)q[k].z; a3 += (double)q[k].w;
            int2 d = rng_s[r + k];
            if (xq >= d.x && xq < d.y)
                Cc4[(size_t)(r0 + r + k) * (WW / 4) + xq] =
                    make_float4((float)a0, (float)a1, (float)a2, (float)a3);
        }
    }
    double2* pp = (double2*)(part + (size_t)c * WW) + xq * 2;
    pp[0] = make_double2(a0, a1);
    pp[1] = make_double2(a2, a3);
}

// in-place exclusive scan of part along chunk axis (per column), COALESCED:
// thread owns a column, consecutive threads -> consecutive addresses
// (R9's transposed one-block-per-column variant was uncoalesced; regressed.
// R12's deletion of this kernel made boxsum latency-bound; regressed.)
__global__ void k_chunkscan(double* __restrict__ part) {
    int x = blockIdx.x * blockDim.x + threadIdx.x;   // WW threads
    double carry = 0.0;
    for (int g = 0; g < NCHUNK / 16; g++) {
        double v[16];
        #pragma unroll
        for (int k = 0; k < 16; k++) v[k] = part[(size_t)(g * 16 + k) * WW + x];
        #pragma unroll
        for (int k = 0; k < 16; k++) { double tv = v[k]; v[k] = carry; carry += tv; }
        #pragma unroll
        for (int k = 0; k < 16; k++) part[(size_t)(g * 16 + k) * WW + x] = v[k];
    }
}

// per-box rectangle sum: 256 threads (4 waves) per box.
// column value = within-chunk fp32 cumsum row + fp64 chunk prefix (>>4:
// CROWS == 16).
__global__ void __launch_bounds__(256) k_boxsum(const float* __restrict__ bbox,
                         const float* __restrict__ obj,
                         const float* __restrict__ Cc,
                         const double* __restrict__ part,
                         double* __restrict__ sc64) {
    int i = blockIdx.x;
    int t = threadIdx.x;
    float4 bb = ((const float4*)bbox)[i];
    int x1 = min(max((int)floorf(bb.x), 0), WW);
    int y1 = min(max((int)floorf(bb.y), 0), HH);
    int x2 = min(max((int)floorf(bb.z), 0), WW);
    int y2 = min(max((int)floorf(bb.w), 0), HH);
    bool h1 = (y1 >= 1), h2 = (y2 >= 1);
    const float*  r2 = Cc   + (size_t)(h2 ? (y2 - 1) : 0) * WW;
    const double* q2 = part + (size_t)(h2 ? ((y2 - 1) >> 4) : 0) * WW;
    const float*  r1 = Cc   + (size_t)(h1 ? (y1 - 1) : 0) * WW;
    const double* q1 = part + (size_t)(h1 ? ((y1 - 1) >> 4) : 0) * WW;
    double s = 0.0;
    for (int x = x1 + t; x < x2; x += 256) {
        double v2 = h2 ? ((double)r2[x] + q2[x]) : 0.0;
        double v1 = h1 ? ((double)r1[x] + q1[x]) : 0.0;
        s += (v2 - v1);
    }
    __shared__ double red[4];
    #pragma unroll
    for (int off = 32; off > 0; off >>= 1) s += __shfl_down(s, off);
    if ((t & 63) == 0) red[t >> 6] = s;
    __syncthreads();
    if (t == 0) {
        double tot = red[0] + red[1] + red[2] + red[3];
        long long cnt = (long long)(y2 - y1) * (long long)(x2 - x1);
        if (cnt < 1) cnt = 1;
        sc64[i] = 0.5 * ((double)obj[i] + tot / (double)cnt);
    }
}

// stable descending rank sort, 8 blocks x 128 threads; per-block LDS score
// copy; sequential j loop -> all lanes broadcast-read the same s[j] (no bank
// conflicts).
__global__ void __launch_bounds__(128) k_rank(const double* __restrict__ sc64,
                                              int* __restrict__ order) {
    __shared__ double s[NB];   // 8 KB
    int t = threadIdx.x;
    for (int k = t; k < NB; k += 128) s[k] = sc64[k];
    __syncthreads();
    int i = blockIdx.x * 128 + t;
    double si = s[i];
    int rank = 0;
    #pragma unroll 8
    for (int j = 0; j < NB; j++) {
        double sj = s[j];
        rank += (sj > si) || (sj == si && j < i);
    }
    order[rank] = i;
}

// IoU(sorted_i, sorted_j) > 0.5 bit matrix via order-indirection (order 4 KB,
// bbox 16 KB — L1/L2 resident). 4096 blocks. One u64 word per 64 j's.
__global__ void k_iou(const int* __restrict__ order, const float* __restrict__ bbox,
                      u64* __restrict__ ioub) {
    int tid = blockIdx.x * blockDim.x + threadIdx.x; // NB*NB threads
    int i = tid >> 10;
    int j = tid & (NB - 1);
    float4 a = ((const float4*)bbox)[order[i]];
    float4 b = ((const float4*)bbox)[order[j]];
    float ai = (a.z - a.x) * (a.w - a.y);
    float aj = (b.z - b.x) * (b.w - b.y);
    float ix1 = fmaxf(a.x, b.x), iy1 = fmaxf(a.y, b.y);
    float ix2 = fminf(a.z, b.z), iy2 = fminf(a.w, b.w);
    float iw = fmaxf(ix2 - ix1, 0.0f), ih = fmaxf(iy2 - iy1, 0.0f);
    float inter = iw * ih;
    float iou_v = inter / (ai + aj - inter);
    bool bit = iou_v > IOU_T;
    u64 m = __ballot(bit);
    if ((threadIdx.x & 63) == 0) ioub[(size_t)i * 16 + (j >> 6)] = m;
}

// greedy grouping, one thread per start, 16 blocks x 64 threads, with the
// final last-argmax + output scatter fused into the LAST block to finish
// (device-scope atomic counter). Register masks + ctz scan walk the SAME
// increasing-j greedy order as the reference (inc updated per add).
// Record rule: rec iff size==K and the last add happened at j <= NB-2
// (check-before-add semantics).
__global__ void __launch_bounds__(64) k_group(const u64* __restrict__ ioub,
                        const int* __restrict__ order,
                        const double* __restrict__ sc64,
                        const int* __restrict__ counts,
                        double* __restrict__ recsc,
                        u64* __restrict__ recsel,
                        int* __restrict__ ctr,
                        float* __restrict__ out) {
    __shared__ double ssd_s[NB];   // 8 KB, sorted scores
    __shared__ int lastflag;
    int t = threadIdx.x;
    int i = blockIdx.x * 64 + t;   // start index (sorted domain)
    for (int k = t; k < NB; k += 64) ssd_s[k] = sc64[order[k]];
    __syncthreads();
    int K = counts[0];
    u64 inc[16], sel[16];
    int wi = i >> 6, bi = i & 63;
    #pragma unroll
    for (int w = 0; w < 16; w++) {
        inc[w] = ioub[(size_t)i * 16 + w];
        sel[w] = (w == wi) ? (1ULL << bi) : 0ULL;
    }
    int size = 1;
    double score = ssd_s[i];
    int last = i;
    #pragma unroll
    for (int w = 0; w < 16; w++) {
        if (w < wi || size >= K) continue;
        u64 avail = ~inc[w];
        if (w == wi) avail &= (bi == 63) ? 0ULL : (~0ULL << (bi + 1));
        while (avail != 0ULL && size < K) {
            int b = __builtin_ctzll(avail);
            int j = (w << 6) + b;
            sel[w] |= 1ULL << b;
            size++;
            score += ssd_s[j];
            last = j;
            const u64* rj = ioub + (size_t)j * 16;
            #pragma unroll
            for (int w2 = 0; w2 < 16; w2++) inc[w2] |= rj[w2];
            avail &= ~inc[w];          // row j's own bits clear b et al.
            avail &= ~(1ULL << b);     // safety
        }
    }
    int rec = (size == K) && (last < NB - 1);
    recsc[i] = rec ? score : -1e300;
    #pragma unroll
    for (int w = 0; w < 16; w++) recsel[(size_t)i * 16 + w] = sel[w];
    __threadfence();               // device-scope release of recsc/recsel
    if (t == 0) lastflag = (atomicAdd(ctr, 1) == (int)gridDim.x - 1);
    __syncthreads();
    if (!lastflag) return;
    __threadfence();               // acquire side: see all blocks' writes
    // final: max recorded score, ties -> LAST index (last-argmax rule)
    double bs = -1e301; int bidx = 0;
    for (int m = 0; m < 16; m++) {
        int k = t * 16 + m;        // increasing k; >= keeps the last
        double v = recsc[k];
        if (v >= bs) { bs = v; bidx = k; }
    }
    #pragma unroll
    for (int off = 32; off > 0; off >>= 1) {
        double ob = __shfl_down(bs, off);
        int oi = __shfl_down(bidx, off);
        if (ob > bs || (ob == bs && oi > bidx)) { bs = ob; bidx = oi; }
    }
    bs = __shfl(bs, 0);
    bidx = __shfl(bidx, 0);
    int any = bs > -1e299;
    for (int k = t; k < NB; k += 64) {
        float v = 0.0f;
        if (any && ((recsel[(size_t)bidx * 16 + (k >> 6)] >> (k & 63)) & 1ULL))
            v = (float)ssd_s[k];
        out[k] = v;
    }
}

// ---------------- host entry ------------------------------------------------

extern "C" void kernel_launch(void* const* d_in, const int* in_sizes, int n_in,
                              void* d_out, int out_size, void* d_ws, size_t ws_size,
                              hipStream_t stream) {
    const float* bbox  = (const float*)d_in[0];
    const float* obj   = (const float*)d_in[1];
    const float* probs = (const float*)d_in[2];
    const int*   counts = (const int*)d_in[3];
    float* out = (float*)d_out;

    char* w = (char*)d_ws;
    double* part    = (double*)(w + OFF_PART);
    double* sc64    = (double*)(w + OFF_SC64);
    int*    order   = (int*)(w + OFF_ORDER);
    int*    ctr     = (int*)(w + OFF_CTR);
    u64*    ioub    = (u64*)(w + OFF_IOU);
    double* recsc   = (double*)(w + OFF_RECSC);
    u64*    recsel  = (u64*)(w + OFF_RECSEL);
    float*  Cc      = (float*)(w + OFF_CC);

    k_stage<<<(NCHUNK * WW / 4) / 256, 256, 0, stream>>>(probs, bbox, part, Cc, ctr);
    k_chunkscan<<<WW / 256, 256, 0, stream>>>(part);
    k_boxsum<<<NB, 256, 0, stream>>>(bbox, obj, Cc, part, sc64);
    k_rank<<<NB / 128, 128, 0, stream>>>(sc64, order);
    k_iou<<<(NB * NB) / 256, 256, 0, stream>>>(order, bbox, ioub);
    k_group<<<NB / 64, 64, 0, stream>>>(ioub, order, sc64, counts, recsc, recsel,
                                        ctr, out);
}